// Round 1
// 299.542 us; speedup vs baseline: 1.2042x; 1.2042x over previous
//
#include <hip/hip_runtime.h>

typedef __bf16 bf16;
typedef __bf16 bf16x2 __attribute__((ext_vector_type(2)));
typedef __bf16 bf16x4 __attribute__((ext_vector_type(4)));
typedef __bf16 bf16x8 __attribute__((ext_vector_type(8)));
typedef float  f32x4  __attribute__((ext_vector_type(4)));
typedef unsigned int uint4v __attribute__((ext_vector_type(4)));

#define MFMA16(a,b,c) __builtin_amdgcn_mfma_f32_16x16x32_bf16(a,b,c,0,0,0)

// Load 8 consecutive f32 and round to bf16x8 (for LDS staging).
__device__ __forceinline__ bf16x8 ld8_f32_to_bf16(const float* __restrict__ p)
{
    f32x4 a = *(const f32x4*)p;
    f32x4 b = *(const f32x4*)(p + 4);
    bf16x8 o;
#pragma unroll
    for (int j = 0; j < 4; j++) { o[j] = (bf16)a[j]; o[4 + j] = (bf16)b[j]; }
    return o;
}

// ---------------------------------------------------------------------------
// QKV GEMM (m97-style, 16x16x32): C[8192x512] = A[8192x512] @ W[512x512]^T.
// A,W are f32 in HBM, converted to bf16 during LDS staging.
// mode 0: bf16 store out[row*512+col]
// mode 1: V^T bf16 store out[((b*8+h)*64+d)*4096 + c]
// Verified layouts: A-frag[m=lane&15][k=quad*8+j], B-frag[n=lane&15][k],
// C/D col=lane&15, row=quad*4+reg.
// ---------------------------------------------------------------------------
__global__ __launch_bounds__(256, 2) void mm_qkv(
    const float* __restrict__ x,  const float* __restrict__ ctx,
    const float* __restrict__ wq, const float* __restrict__ wk,
    const float* __restrict__ wv,
    bf16* __restrict__ Qb, bf16* __restrict__ Kb, bf16* __restrict__ Vtb)
{
    __shared__ bf16 Al[128 * 40];
    __shared__ bf16 Wl[128 * 40];

    const float* A; const float* W; bf16* out; int mode;
    if (blockIdx.z == 0)      { A = x;   W = wq; out = Qb;  mode = 0; }
    else if (blockIdx.z == 1) { A = ctx; W = wk; out = Kb;  mode = 0; }
    else                      { A = ctx; W = wv; out = Vtb; mode = 1; }

    const int tid  = threadIdx.x;
    const int lane = tid & 63;
    const int w    = tid >> 6;
    const int wr   = w >> 1, wc = w & 1;
    const int bx   = blockIdx.x, by = blockIdx.y;
    const int q    = lane >> 4, m0 = lane & 15;

    f32x4 acc[4][4];
#pragma unroll
    for (int i = 0; i < 4; i++)
#pragma unroll
        for (int j = 0; j < 4; j++)
#pragma unroll
            for (int r = 0; r < 4; r++) acc[i][j][r] = 0.f;

    const int r0 = tid >> 2;
    const int c0 = (tid & 3) * 8;
    const float* Ab = A + (size_t)(by * 128) * 512;
    const float* Wb = W + (size_t)(bx * 128) * 512;

    for (int k0 = 0; k0 < 512; k0 += 32) {
        *(bf16x8*)&Al[r0 * 40 + c0]        = ld8_f32_to_bf16(Ab + (size_t)r0 * 512 + k0 + c0);
        *(bf16x8*)&Al[(r0 + 64) * 40 + c0] = ld8_f32_to_bf16(Ab + (size_t)(r0 + 64) * 512 + k0 + c0);
        *(bf16x8*)&Wl[r0 * 40 + c0]        = ld8_f32_to_bf16(Wb + (size_t)r0 * 512 + k0 + c0);
        *(bf16x8*)&Wl[(r0 + 64) * 40 + c0] = ld8_f32_to_bf16(Wb + (size_t)(r0 + 64) * 512 + k0 + c0);
        __syncthreads();

        bf16x8 af[4], wf[4];
#pragma unroll
        for (int mt = 0; mt < 4; mt++)
            af[mt] = *(const bf16x8*)&Al[(wr * 64 + mt * 16 + m0) * 40 + q * 8];
#pragma unroll
        for (int nt = 0; nt < 4; nt++)
            wf[nt] = *(const bf16x8*)&Wl[(wc * 64 + nt * 16 + m0) * 40 + q * 8];
#pragma unroll
        for (int mt = 0; mt < 4; mt++)
#pragma unroll
            for (int nt = 0; nt < 4; nt++)
                acc[mt][nt] = MFMA16(af[mt], wf[nt], acc[mt][nt]);
        __syncthreads();
    }

#pragma unroll
    for (int nt = 0; nt < 4; nt++) {
        const int col = bx * 128 + wc * 64 + nt * 16 + m0;
#pragma unroll
        for (int mt = 0; mt < 4; mt++) {
#pragma unroll
            for (int r = 0; r < 4; r++) {
                const int row = by * 128 + wr * 64 + mt * 16 + q * 4 + r;
                const bf16 v16 = (bf16)acc[mt][nt][r];
                if (mode == 0) {
                    out[(size_t)row * 512 + col] = v16;
                } else {
                    const int bb = row >> 12, c = row & 4095;
                    const int hh = col >> 6,  d = col & 63;
                    out[(size_t)((bb * 8 + hh) * 64 + d) * 4096 + c] = v16;
                }
            }
        }
    }
}

// ---------------------------------------------------------------------------
// Out-proj GEMM: out_f32[8192x512] = Ob_bf16[8192x512] @ wout_f32^T + bout.
// ---------------------------------------------------------------------------
__global__ __launch_bounds__(256, 2) void mm_oproj(
    const bf16* __restrict__ Ob, const float* __restrict__ wout,
    const float* __restrict__ bout, float* __restrict__ out)
{
    __shared__ bf16 Al[128 * 40];
    __shared__ bf16 Wl[128 * 40];

    const int tid  = threadIdx.x;
    const int lane = tid & 63;
    const int w    = tid >> 6;
    const int wr   = w >> 1, wc = w & 1;
    const int bx   = blockIdx.x, by = blockIdx.y;
    const int q    = lane >> 4, m0 = lane & 15;

    f32x4 acc[4][4];
#pragma unroll
    for (int i = 0; i < 4; i++)
#pragma unroll
        for (int j = 0; j < 4; j++)
#pragma unroll
            for (int r = 0; r < 4; r++) acc[i][j][r] = 0.f;

    const int r0 = tid >> 2;
    const int c0 = (tid & 3) * 8;
    const bf16*  Ab = Ob   + (size_t)(by * 128) * 512;
    const float* Wb = wout + (size_t)(bx * 128) * 512;

    for (int k0 = 0; k0 < 512; k0 += 32) {
        *(bf16x8*)&Al[r0 * 40 + c0]        = *(const bf16x8*)(Ab + (size_t)r0 * 512 + k0 + c0);
        *(bf16x8*)&Al[(r0 + 64) * 40 + c0] = *(const bf16x8*)(Ab + (size_t)(r0 + 64) * 512 + k0 + c0);
        *(bf16x8*)&Wl[r0 * 40 + c0]        = ld8_f32_to_bf16(Wb + (size_t)r0 * 512 + k0 + c0);
        *(bf16x8*)&Wl[(r0 + 64) * 40 + c0] = ld8_f32_to_bf16(Wb + (size_t)(r0 + 64) * 512 + k0 + c0);
        __syncthreads();

        bf16x8 af[4], wf[4];
#pragma unroll
        for (int mt = 0; mt < 4; mt++)
            af[mt] = *(const bf16x8*)&Al[(wr * 64 + mt * 16 + m0) * 40 + q * 8];
#pragma unroll
        for (int nt = 0; nt < 4; nt++)
            wf[nt] = *(const bf16x8*)&Wl[(wc * 64 + nt * 16 + m0) * 40 + q * 8];
#pragma unroll
        for (int mt = 0; mt < 4; mt++)
#pragma unroll
            for (int nt = 0; nt < 4; nt++)
                acc[mt][nt] = MFMA16(af[mt], wf[nt], acc[mt][nt]);
        __syncthreads();
    }

#pragma unroll
    for (int nt = 0; nt < 4; nt++) {
        const int col = bx * 128 + wc * 64 + nt * 16 + m0;
        const float bv = bout[col];
#pragma unroll
        for (int mt = 0; mt < 4; mt++) {
#pragma unroll
            for (int r = 0; r < 4; r++) {
                const int row = by * 128 + wr * 64 + mt * 16 + q * 4 + r;
                out[(size_t)row * 512 + col] = acc[mt][nt][r] + bv;
            }
        }
    }
}

// ---------------------------------------------------------------------------
// Flash attention, swapped-operand 16x16x32 MFMA. Wave = 16 q-rows, ONE q-row
// per lane (col index of S^T). Per 64-c chunk:
//   S^T = mfma(K, Q)  -> lane (quad,m0) holds S[c=ct*16+quad*4+r][row m0]
//   softmax: 15 in-lane ops + 2 shfl_xor (masks 16,32); scalar m/l state
//   P^T B-frags built in-register: pack bf16 pairs + 16-shfl cross-quad
//     exchange (dst slot cs needs c=cs*32+q*8+j, held by quads 2*(q&1)+phi,
//     register group cs*2+(q>>1), same m0)
//   O^T += mfma(V^T, P^T) -> lane holds O[row m0][d=dt*16+quad*4+r]
// K/V double-buffered in LDS: ONE barrier per chunk, staging overlaps compute.
// No P LDS buffer, no mid barrier.
// ---------------------------------------------------------------------------
__global__ __launch_bounds__(256, 2) void fa_attn(
    const bf16* __restrict__ Qb, const bf16* __restrict__ Kb,
    const bf16* __restrict__ Vtb, bf16* __restrict__ Ob)
{
    __shared__ bf16 Kl[2][64 * 72];     // K chunk [c][d], double-buffered
    __shared__ bf16 Vl[2][64 * 72];     // V^T chunk [d][c], double-buffered

    const int tid  = threadIdx.x;
    const int lane = tid & 63;
    const int w    = tid >> 6;
    const int q    = lane >> 4;
    const int m0   = lane & 15;
    const int b    = blockIdx.z, h0 = blockIdx.y;
    const int qg   = blockIdx.x * 64 + w * 16;

    // Q fragment (B-role): lane holds Q[row=qg+m0][d=q*8+j (+32)], pre-scaled.
    bf16x8 af[2];
    const bf16* qp = Qb + (size_t)(b * 4096 + qg + m0) * 512 + h0 * 64 + q * 8;
#pragma unroll
    for (int kd = 0; kd < 2; kd++) {
        bf16x8 t = *(const bf16x8*)(qp + kd * 32);
#pragma unroll
        for (int j = 0; j < 8; j++) t[j] = (bf16)((float)t[j] * 0.125f);  // exact
        af[kd] = t;
    }

    f32x4 oc[4];
#pragma unroll
    for (int dt = 0; dt < 4; dt++)
#pragma unroll
        for (int r = 0; r < 4; r++) oc[dt][r] = 0.f;
    float mrun = -1e30f, lrun = 0.f;

    const int srow = tid >> 2;
    const int scol = (tid & 3) * 16;
    const bf16* Kg = Kb  + (size_t)(b * 4096) * 512 + h0 * 64;
    const bf16* Vg = Vtb + (size_t)(b * 8 + h0) * 64 * 4096;

#define STAGE(buf, cb_) do { \
    *(bf16x8*)&Kl[buf][srow * 72 + scol]     = *(const bf16x8*)(Kg + (size_t)((cb_) + srow) * 512 + scol); \
    *(bf16x8*)&Kl[buf][srow * 72 + scol + 8] = *(const bf16x8*)(Kg + (size_t)((cb_) + srow) * 512 + scol + 8); \
    *(bf16x8*)&Vl[buf][srow * 72 + scol]     = *(const bf16x8*)(Vg + (size_t)srow * 4096 + (cb_) + scol); \
    *(bf16x8*)&Vl[buf][srow * 72 + scol + 8] = *(const bf16x8*)(Vg + (size_t)srow * 4096 + (cb_) + scol + 8); \
} while (0)

    STAGE(0, 0);
    int cur = 0;

    const int L0 = ((lane & 16) << 1) | m0;   // src lane: quad 2*(q&1), same m0
    const int L1 = L0 + 16;                   // src lane: quad 2*(q&1)+1
    const bool hi = lane >= 32;               // q>>1: selects register group

    for (int cb = 0; cb < 4096; cb += 64) {
        __syncthreads();
        if (cb + 64 < 4096) STAGE(cur ^ 1, cb + 64);

        const bf16* Kc = &Kl[cur][0];
        const bf16* Vc = &Vl[cur][0];

        // S^T = K.Q^T (A=K rows=c, B=Q cols=q-rows)
        f32x4 st[4];
#pragma unroll
        for (int ct = 0; ct < 4; ct++) {
#pragma unroll
            for (int r = 0; r < 4; r++) st[ct][r] = 0.f;
            bf16x8 k0 = *(const bf16x8*)&Kc[(ct * 16 + m0) * 72 + q * 8];
            bf16x8 k1 = *(const bf16x8*)&Kc[(ct * 16 + m0) * 72 + 32 + q * 8];
            st[ct] = MFMA16(k0, af[0], st[ct]);
            st[ct] = MFMA16(k1, af[1], st[ct]);
        }

        // online softmax: one q-row per lane, 16 c-values in-lane,
        // remaining 48 in the other 3 quads (shfl_xor 16, 32)
        float mx = st[0][0];
#pragma unroll
        for (int ct = 0; ct < 4; ct++)
#pragma unroll
            for (int r = 0; r < 4; r++) mx = fmaxf(mx, st[ct][r]);
        mx = fmaxf(mx, __shfl_xor(mx, 16));
        mx = fmaxf(mx, __shfl_xor(mx, 32));

        const float mnew = fmaxf(mrun, mx);
        const float al = __expf(mrun - mnew);
        mrun = mnew;

        float p[4][4];
        float rs = 0.f;
#pragma unroll
        for (int ct = 0; ct < 4; ct++)
#pragma unroll
            for (int r = 0; r < 4; r++) {
                p[ct][r] = __expf(st[ct][r] - mnew);
                rs += p[ct][r];
            }
        rs += __shfl_xor(rs, 16);
        rs += __shfl_xor(rs, 32);
        lrun = lrun * al + rs;
#pragma unroll
        for (int dt = 0; dt < 4; dt++)
#pragma unroll
            for (int r = 0; r < 4; r++) oc[dt][r] *= al;

        // pack P values (c = ct*16+q*4+r for row m0) into bf16-pair dwords
        unsigned int pd[4][2];
#pragma unroll
        for (int ct = 0; ct < 4; ct++)
#pragma unroll
            for (int t = 0; t < 2; t++) {
                bf16x2 pr;
                pr[0] = (bf16)p[ct][2 * t];
                pr[1] = (bf16)p[ct][2 * t + 1];
                pd[ct][t] = __builtin_bit_cast(unsigned int, pr);
            }

        // cross-quad exchange -> P^T B-frag: lane needs P[m0][cs*32+q*8+j]
        bf16x8 pf[2];
#pragma unroll
        for (int cs = 0; cs < 2; cs++) {
            const unsigned int a0 = (unsigned int)__shfl((int)pd[2 * cs][0],     L0);
            const unsigned int a1 = (unsigned int)__shfl((int)pd[2 * cs + 1][0], L0);
            const unsigned int b0 = (unsigned int)__shfl((int)pd[2 * cs][1],     L0);
            const unsigned int b1 = (unsigned int)__shfl((int)pd[2 * cs + 1][1], L0);
            const unsigned int c0 = (unsigned int)__shfl((int)pd[2 * cs][0],     L1);
            const unsigned int c1 = (unsigned int)__shfl((int)pd[2 * cs + 1][0], L1);
            const unsigned int d0 = (unsigned int)__shfl((int)pd[2 * cs][1],     L1);
            const unsigned int d1 = (unsigned int)__shfl((int)pd[2 * cs + 1][1], L1);
            uint4v u;
            u[0] = hi ? a1 : a0;
            u[1] = hi ? b1 : b0;
            u[2] = hi ? c1 : c0;
            u[3] = hi ? d1 : d0;
            pf[cs] = __builtin_bit_cast(bf16x8, u);
        }

        // O^T += V^T.P^T (A=V^T rows=d, B=P^T cols=q-rows)
#pragma unroll
        for (int dt = 0; dt < 4; dt++) {
            bf16x8 v0 = *(const bf16x8*)&Vc[(dt * 16 + m0) * 72 + q * 8];
            bf16x8 v1 = *(const bf16x8*)&Vc[(dt * 16 + m0) * 72 + 32 + q * 8];
            oc[dt] = MFMA16(v0, pf[0], oc[dt]);
            oc[dt] = MFMA16(v1, pf[1], oc[dt]);
        }
        cur ^= 1;
    }
#undef STAGE

    // lane holds O[row m0][d = dt*16 + q*4 + r] -> 8B vector stores
    const float rli = 1.0f / lrun;
    bf16* ob = Ob + (size_t)(b * 4096 + qg) * 512 + h0 * 64;
#pragma unroll
    for (int dt = 0; dt < 4; dt++) {
        bf16x4 o4;
#pragma unroll
        for (int r = 0; r < 4; r++) o4[r] = (bf16)(oc[dt][r] * rli);
        *(bf16x4*)&ob[(size_t)m0 * 512 + dt * 16 + q * 4] = o4;
    }
}

__global__ void ws_sig11(float* out) { if (threadIdx.x == 0) out[0] = 777.0f; }

// ---------------------------------------------------------------------------
extern "C" void kernel_launch(void* const* d_in, const int* in_sizes, int n_in,
                              void* d_out, int out_size, void* d_ws, size_t ws_size,
                              hipStream_t stream)
{
    const float* x    = (const float*)d_in[0];   // [2,4096,512] f32
    const float* ctx  = (const float*)d_in[1];   // [2,4096,512] f32
    const float* wq   = (const float*)d_in[2];   // [512,512] f32 [out][in]
    const float* wk   = (const float*)d_in[3];
    const float* wv   = (const float*)d_in[4];
    const float* wout = (const float*)d_in[5];
    const float* bout = (const float*)d_in[6];   // [512] f32
    float* out = (float*)d_out;                  // [2,4096,512] f32

    char* ws = (char*)d_ws;
    const size_t MB = 1024 * 1024;
    const size_t SZ = (size_t)8192 * 512 * sizeof(bf16);   // 8 MiB per buffer
    if (ws_size < 32 * MB) {
        ws_sig11<<<dim3(1), dim3(64), 0, stream>>>(out);
        return;
    }

    bf16* Qb  = (bf16*)(ws);            // [B*S, 512]
    bf16* Kb  = (bf16*)(ws + SZ);       // [B*C, 512]
    bf16* Vtb = (bf16*)(ws + 2 * SZ);   // [B,H,64,C] transposed V
    bf16* Ob  = (bf16*)(ws + 3 * SZ);   // [B*S, 512]

    mm_qkv  <<<dim3(4, 64, 3), dim3(256), 0, stream>>>(x, ctx, wq, wk, wv, Qb, Kb, Vtb);
    fa_attn <<<dim3(64, 8, 2), dim3(256), 0, stream>>>(Qb, Kb, Vtb, Ob);
    mm_oproj<<<dim3(4, 64, 1), dim3(256), 0, stream>>>(Ob, wout, bout, out);
}

// Round 2
// 244.914 us; speedup vs baseline: 1.4729x; 1.2230x over previous
//
#include <hip/hip_runtime.h>

typedef __bf16 bf16;
typedef __bf16 bf16x2 __attribute__((ext_vector_type(2)));
typedef __bf16 bf16x4 __attribute__((ext_vector_type(4)));
typedef __bf16 bf16x8 __attribute__((ext_vector_type(8)));
typedef float  f32x4  __attribute__((ext_vector_type(4)));
typedef float  f32x16 __attribute__((ext_vector_type(16)));
typedef unsigned int uint4v __attribute__((ext_vector_type(4)));

#define MFMA16(a,b,c) __builtin_amdgcn_mfma_f32_16x16x32_bf16(a,b,c,0,0,0)
#define MFMA32(a,b,c) __builtin_amdgcn_mfma_f32_32x32x16_bf16(a,b,c,0,0,0)

// Load 8 consecutive f32 and round to bf16x8 (for LDS staging).
__device__ __forceinline__ bf16x8 ld8_f32_to_bf16(const float* __restrict__ p)
{
    f32x4 a = *(const f32x4*)p;
    f32x4 b = *(const f32x4*)(p + 4);
    bf16x8 o;
#pragma unroll
    for (int j = 0; j < 4; j++) { o[j] = (bf16)a[j]; o[4 + j] = (bf16)b[j]; }
    return o;
}

// ---------------------------------------------------------------------------
// QKV GEMM (m97-style, 16x16x32): C[8192x512] = A[8192x512] @ W[512x512]^T.
// ---------------------------------------------------------------------------
__global__ __launch_bounds__(256, 2) void mm_qkv(
    const float* __restrict__ x,  const float* __restrict__ ctx,
    const float* __restrict__ wq, const float* __restrict__ wk,
    const float* __restrict__ wv,
    bf16* __restrict__ Qb, bf16* __restrict__ Kb, bf16* __restrict__ Vtb)
{
    __shared__ bf16 Al[128 * 40];
    __shared__ bf16 Wl[128 * 40];

    const float* A; const float* W; bf16* out; int mode;
    if (blockIdx.z == 0)      { A = x;   W = wq; out = Qb;  mode = 0; }
    else if (blockIdx.z == 1) { A = ctx; W = wk; out = Kb;  mode = 0; }
    else                      { A = ctx; W = wv; out = Vtb; mode = 1; }

    const int tid  = threadIdx.x;
    const int lane = tid & 63;
    const int w    = tid >> 6;
    const int wr   = w >> 1, wc = w & 1;
    const int bx   = blockIdx.x, by = blockIdx.y;
    const int q    = lane >> 4, m0 = lane & 15;

    f32x4 acc[4][4];
#pragma unroll
    for (int i = 0; i < 4; i++)
#pragma unroll
        for (int j = 0; j < 4; j++)
#pragma unroll
            for (int r = 0; r < 4; r++) acc[i][j][r] = 0.f;

    const int r0 = tid >> 2;
    const int c0 = (tid & 3) * 8;
    const float* Ab = A + (size_t)(by * 128) * 512;
    const float* Wb = W + (size_t)(bx * 128) * 512;

    for (int k0 = 0; k0 < 512; k0 += 32) {
        *(bf16x8*)&Al[r0 * 40 + c0]        = ld8_f32_to_bf16(Ab + (size_t)r0 * 512 + k0 + c0);
        *(bf16x8*)&Al[(r0 + 64) * 40 + c0] = ld8_f32_to_bf16(Ab + (size_t)(r0 + 64) * 512 + k0 + c0);
        *(bf16x8*)&Wl[r0 * 40 + c0]        = ld8_f32_to_bf16(Wb + (size_t)r0 * 512 + k0 + c0);
        *(bf16x8*)&Wl[(r0 + 64) * 40 + c0] = ld8_f32_to_bf16(Wb + (size_t)(r0 + 64) * 512 + k0 + c0);
        __syncthreads();

        bf16x8 af[4], wf[4];
#pragma unroll
        for (int mt = 0; mt < 4; mt++)
            af[mt] = *(const bf16x8*)&Al[(wr * 64 + mt * 16 + m0) * 40 + q * 8];
#pragma unroll
        for (int nt = 0; nt < 4; nt++)
            wf[nt] = *(const bf16x8*)&Wl[(wc * 64 + nt * 16 + m0) * 40 + q * 8];
#pragma unroll
        for (int mt = 0; mt < 4; mt++)
#pragma unroll
            for (int nt = 0; nt < 4; nt++)
                acc[mt][nt] = MFMA16(af[mt], wf[nt], acc[mt][nt]);
        __syncthreads();
    }

#pragma unroll
    for (int nt = 0; nt < 4; nt++) {
        const int col = bx * 128 + wc * 64 + nt * 16 + m0;
#pragma unroll
        for (int mt = 0; mt < 4; mt++) {
#pragma unroll
            for (int r = 0; r < 4; r++) {
                const int row = by * 128 + wr * 64 + mt * 16 + q * 4 + r;
                const bf16 v16 = (bf16)acc[mt][nt][r];
                if (mode == 0) {
                    out[(size_t)row * 512 + col] = v16;
                } else {
                    const int bb = row >> 12, c = row & 4095;
                    const int hh = col >> 6,  d = col & 63;
                    out[(size_t)((bb * 8 + hh) * 64 + d) * 4096 + c] = v16;
                }
            }
        }
    }
}

// ---------------------------------------------------------------------------
// Out-proj GEMM: out_f32[8192x512] = Ob_bf16[8192x512] @ wout_f32^T + bout.
// ---------------------------------------------------------------------------
__global__ __launch_bounds__(256, 2) void mm_oproj(
    const bf16* __restrict__ Ob, const float* __restrict__ wout,
    const float* __restrict__ bout, float* __restrict__ out)
{
    __shared__ bf16 Al[128 * 40];
    __shared__ bf16 Wl[128 * 40];

    const int tid  = threadIdx.x;
    const int lane = tid & 63;
    const int w    = tid >> 6;
    const int wr   = w >> 1, wc = w & 1;
    const int bx   = blockIdx.x, by = blockIdx.y;
    const int q    = lane >> 4, m0 = lane & 15;

    f32x4 acc[4][4];
#pragma unroll
    for (int i = 0; i < 4; i++)
#pragma unroll
        for (int j = 0; j < 4; j++)
#pragma unroll
            for (int r = 0; r < 4; r++) acc[i][j][r] = 0.f;

    const int r0 = tid >> 2;
    const int c0 = (tid & 3) * 8;
    const bf16*  Ab = Ob   + (size_t)(by * 128) * 512;
    const float* Wb = wout + (size_t)(bx * 128) * 512;

    for (int k0 = 0; k0 < 512; k0 += 32) {
        *(bf16x8*)&Al[r0 * 40 + c0]        = *(const bf16x8*)(Ab + (size_t)r0 * 512 + k0 + c0);
        *(bf16x8*)&Al[(r0 + 64) * 40 + c0] = *(const bf16x8*)(Ab + (size_t)(r0 + 64) * 512 + k0 + c0);
        *(bf16x8*)&Wl[r0 * 40 + c0]        = ld8_f32_to_bf16(Wb + (size_t)r0 * 512 + k0 + c0);
        *(bf16x8*)&Wl[(r0 + 64) * 40 + c0] = ld8_f32_to_bf16(Wb + (size_t)(r0 + 64) * 512 + k0 + c0);
        __syncthreads();

        bf16x8 af[4], wf[4];
#pragma unroll
        for (int mt = 0; mt < 4; mt++)
            af[mt] = *(const bf16x8*)&Al[(wr * 64 + mt * 16 + m0) * 40 + q * 8];
#pragma unroll
        for (int nt = 0; nt < 4; nt++)
            wf[nt] = *(const bf16x8*)&Wl[(wc * 64 + nt * 16 + m0) * 40 + q * 8];
#pragma unroll
        for (int mt = 0; mt < 4; mt++)
#pragma unroll
            for (int nt = 0; nt < 4; nt++)
                acc[mt][nt] = MFMA16(af[mt], wf[nt], acc[mt][nt]);
        __syncthreads();
    }

#pragma unroll
    for (int nt = 0; nt < 4; nt++) {
        const int col = bx * 128 + wc * 64 + nt * 16 + m0;
        const float bv = bout[col];
#pragma unroll
        for (int mt = 0; mt < 4; mt++) {
#pragma unroll
            for (int r = 0; r < 4; r++) {
                const int row = by * 128 + wr * 64 + mt * 16 + q * 4 + r;
                out[(size_t)row * 512 + col] = acc[mt][nt][r] + bv;
            }
        }
    }
}

// ---------------------------------------------------------------------------
// Flash attention, 32x32x16 MFMA, swapped operands. Wave = 32 q-rows, ONE
// q-row per lane (col = lane&31 of S^T); k-half hd = lane>>5.
// Layouts (32x32x16): A[m=lane&31][k=hd*8+j], B[k=hd*8+j][n=lane&31],
// C/D col=lane&31, row=(reg&3)+8*(reg>>2)+4*hd  [verified m74/m101].
// Per 64-c chunk:
//   S^T = mfma32(K, Q): st[ct] holds S[c=ct*32+(r&3)+8*(r>>2)+4hd][qrow]
//   softmax: 31 in-lane ops + shfl_xor(32) for max and sum; scalar m/l
//   P^T B-frag[ks] needs c in [16ks+8hd, +7]: first 4-block = lanes<32
//     group 2(ks&1), second = lanes>=32 group 2(ks&1)+1 (same lane&31).
//     Pack exp() pairs to bf16 dwords; 2 shfl_xor(32) per ks.
//   O^T += mfma32(V^T, P^T): lane holds O[qrow][d=dt*32+(r&3)+8*(r>>2)+4hd]
// K/V double-buffered in LDS; ONE barrier per chunk.
// ---------------------------------------------------------------------------
__global__ __launch_bounds__(256, 2) void fa_attn(
    const bf16* __restrict__ Qb, const bf16* __restrict__ Kb,
    const bf16* __restrict__ Vtb, bf16* __restrict__ Ob)
{
    __shared__ bf16 Kl[2][64 * 72];     // K chunk [c][d]
    __shared__ bf16 Vl[2][64 * 72];     // V^T chunk [d][c]

    const int tid  = threadIdx.x;
    const int lane = tid & 63;
    const int w    = tid >> 6;
    const int n0   = lane & 31;         // q-row / A-row within tile
    const int hd   = lane >> 5;         // k-half
    const int b    = blockIdx.z, h0 = blockIdx.y;
    const int qg   = blockIdx.x * 128 + w * 32;

    // Q B-frags: lane holds Q[qg+n0][d = ks*16 + hd*8 + j], pre-scaled.
    bf16x8 qf[4];
    const bf16* qp = Qb + (size_t)(b * 4096 + qg + n0) * 512 + h0 * 64 + hd * 8;
#pragma unroll
    for (int ks = 0; ks < 4; ks++) {
        bf16x8 t = *(const bf16x8*)(qp + ks * 16);
#pragma unroll
        for (int j = 0; j < 8; j++) t[j] = (bf16)((float)t[j] * 0.125f);  // exact
        qf[ks] = t;
    }

    f32x16 oc[2];
#pragma unroll
    for (int dt = 0; dt < 2; dt++)
#pragma unroll
        for (int r = 0; r < 16; r++) oc[dt][r] = 0.f;
    float mrun = -1e30f, lrun = 0.f;

    const int srow = tid >> 2;
    const int scol = (tid & 3) * 16;
    const bf16* Kg = Kb  + (size_t)(b * 4096) * 512 + h0 * 64;
    const bf16* Vg = Vtb + (size_t)(b * 8 + h0) * 64 * 4096;

#define STAGE(buf, cb_) do { \
    *(bf16x8*)&Kl[buf][srow * 72 + scol]     = *(const bf16x8*)(Kg + (size_t)((cb_) + srow) * 512 + scol); \
    *(bf16x8*)&Kl[buf][srow * 72 + scol + 8] = *(const bf16x8*)(Kg + (size_t)((cb_) + srow) * 512 + scol + 8); \
    *(bf16x8*)&Vl[buf][srow * 72 + scol]     = *(const bf16x8*)(Vg + (size_t)srow * 4096 + (cb_) + scol); \
    *(bf16x8*)&Vl[buf][srow * 72 + scol + 8] = *(const bf16x8*)(Vg + (size_t)srow * 4096 + (cb_) + scol + 8); \
} while (0)

    STAGE(0, 0);
    int cur = 0;

    for (int cb = 0; cb < 4096; cb += 64) {
        __syncthreads();
        if (cb + 64 < 4096) STAGE(cur ^ 1, cb + 64);

        const bf16* Kc = &Kl[cur][0];
        const bf16* Vc = &Vl[cur][0];

        // S^T = K.Q^T
        f32x16 st[2];
#pragma unroll
        for (int ct = 0; ct < 2; ct++) {
#pragma unroll
            for (int r = 0; r < 16; r++) st[ct][r] = 0.f;
#pragma unroll
            for (int ks = 0; ks < 4; ks++) {
                bf16x8 kf = *(const bf16x8*)&Kc[(ct * 32 + n0) * 72 + ks * 16 + hd * 8];
                st[ct] = MFMA32(kf, qf[ks], st[ct]);
            }
        }

        // online softmax: one q-row per lane; 32 values in-lane, 32 in lane^32
        float mx = st[0][0];
#pragma unroll
        for (int ct = 0; ct < 2; ct++)
#pragma unroll
            for (int r = 0; r < 16; r++) mx = fmaxf(mx, st[ct][r]);
        mx = fmaxf(mx, __shfl_xor(mx, 32));

        const float mnew = fmaxf(mrun, mx);
        const float al = __expf(mrun - mnew);
        mrun = mnew;

        // exp, row-sum, and pack bf16 pairs: pd[ct][g][t] = (c=ct*32+8g+4hd+2t, +1)
        unsigned int pd[2][4][2];
        float rs = 0.f;
#pragma unroll
        for (int ct = 0; ct < 2; ct++)
#pragma unroll
            for (int g = 0; g < 4; g++)
#pragma unroll
                for (int t = 0; t < 2; t++) {
                    const float e0 = __expf(st[ct][4 * g + 2 * t]     - mnew);
                    const float e1 = __expf(st[ct][4 * g + 2 * t + 1] - mnew);
                    rs += e0 + e1;
                    bf16x2 pr; pr[0] = (bf16)e0; pr[1] = (bf16)e1;
                    pd[ct][g][t] = __builtin_bit_cast(unsigned int, pr);
                }
        rs += __shfl_xor(rs, 32);
        lrun = lrun * al + rs;
#pragma unroll
        for (int dt = 0; dt < 2; dt++)
#pragma unroll
            for (int r = 0; r < 16; r++) oc[dt][r] *= al;

        // P^T B-frags + PV. For frag ks: ct=ks>>1, g0=2*(ks&1), g1=g0+1.
        // dest hd=0: u = {own[g0], recv}, dest hd=1: u = {recv, own[g1]};
        // each lane SENDS its other group (hd=0 sends g1, hd=1 sends g0).
#pragma unroll
        for (int ks = 0; ks < 4; ks++) {
            const int ct = ks >> 1;
            const int g0 = 2 * (ks & 1), g1 = g0 + 1;
            const unsigned int own0  = hd ? pd[ct][g1][0] : pd[ct][g0][0];
            const unsigned int own1  = hd ? pd[ct][g1][1] : pd[ct][g0][1];
            const unsigned int send0 = hd ? pd[ct][g0][0] : pd[ct][g1][0];
            const unsigned int send1 = hd ? pd[ct][g0][1] : pd[ct][g1][1];
            const unsigned int r0 = (unsigned int)__shfl_xor((int)send0, 32);
            const unsigned int r1 = (unsigned int)__shfl_xor((int)send1, 32);
            uint4v u;
            u[0] = hd ? r0 : own0;
            u[1] = hd ? r1 : own1;
            u[2] = hd ? own0 : r0;
            u[3] = hd ? own1 : r1;
            const bf16x8 pf = __builtin_bit_cast(bf16x8, u);
#pragma unroll
            for (int dt = 0; dt < 2; dt++) {
                bf16x8 vf = *(const bf16x8*)&Vc[(dt * 32 + n0) * 72 + ks * 16 + hd * 8];
                oc[dt] = MFMA32(vf, pf, oc[dt]);
            }
        }
        cur ^= 1;
    }
#undef STAGE

    // lane holds O[qrow=n0][d = dt*32 + (r&3) + 8*(r>>2) + 4*hd]
    const float rli = 1.0f / lrun;
    bf16* ob = Ob + (size_t)(b * 4096 + qg + n0) * 512 + h0 * 64;
#pragma unroll
    for (int dt = 0; dt < 2; dt++)
#pragma unroll
        for (int rq = 0; rq < 4; rq++) {
            bf16x4 o4;
#pragma unroll
            for (int i = 0; i < 4; i++) o4[i] = (bf16)(oc[dt][4 * rq + i] * rli);
            *(bf16x4*)&ob[dt * 32 + rq * 8 + hd * 4] = o4;
        }
}

__global__ void ws_sig11(float* out) { if (threadIdx.x == 0) out[0] = 777.0f; }

// ---------------------------------------------------------------------------
extern "C" void kernel_launch(void* const* d_in, const int* in_sizes, int n_in,
                              void* d_out, int out_size, void* d_ws, size_t ws_size,
                              hipStream_t stream)
{
    const float* x    = (const float*)d_in[0];   // [2,4096,512] f32
    const float* ctx  = (const float*)d_in[1];   // [2,4096,512] f32
    const float* wq   = (const float*)d_in[2];   // [512,512] f32 [out][in]
    const float* wk   = (const float*)d_in[3];
    const float* wv   = (const float*)d_in[4];
    const float* wout = (const float*)d_in[5];
    const float* bout = (const float*)d_in[6];   // [512] f32
    float* out = (float*)d_out;                  // [2,4096,512] f32

    char* ws = (char*)d_ws;
    const size_t MB = 1024 * 1024;
    const size_t SZ = (size_t)8192 * 512 * sizeof(bf16);   // 8 MiB per buffer
    if (ws_size < 32 * MB) {
        ws_sig11<<<dim3(1), dim3(64), 0, stream>>>(out);
        return;
    }

    bf16* Qb  = (bf16*)(ws);            // [B*S, 512]
    bf16* Kb  = (bf16*)(ws + SZ);       // [B*C, 512]
    bf16* Vtb = (bf16*)(ws + 2 * SZ);   // [B,H,64,C] transposed V
    bf16* Ob  = (bf16*)(ws + 3 * SZ);   // [B*S, 512]

    mm_qkv  <<<dim3(4, 64, 3), dim3(256), 0, stream>>>(x, ctx, wq, wk, wv, Qb, Kb, Vtb);
    fa_attn <<<dim3(32, 8, 2), dim3(256), 0, stream>>>(Qb, Kb, Vtb, Ob);
    mm_oproj<<<dim3(4, 64, 1), dim3(256), 0, stream>>>(Ob, wout, bout, out);
}